// Round 15
// baseline (4045.198 us; speedup 1.0000x reference)
//
#include <hip/hip_runtime.h>

// ---------------------------------------------------------------------------
// Bidirectional stacked GRU decoder. B=64, S=512, I=H=512, L=2. f32 I/O.
//
// Round-15 = R11 sync/ring protocol, dual-beta time-multiplexed WGs:
//  - 128 WGs x 128 thr = l(2) x d(2) x cb(32). Each WG serves BOTH beta
//    batch-half pipelines (same weights!): per t, phase be=0 then be=1,
//    each phase = {poll, ring read, 96 MFMA, gate epi, publish, flag}.
//    beta0's sync round-trip (publish->flag->detect, ~2-3us) hides under
//    beta1's phase work and vice versa.
//  - weights (Wih+Whh 16-col slices, bf16 [gate][kk][lane][8]) in LDS once.
//  - dout staged in LDS (douts[be][8][32][20]), flushed every 8 steps ->
//    publish vmcnt(0) drains only the 8B ring store.
//  - rings/flags/guards BIT-IDENTICAL to R11 (8 gids, depth-8 bf16 ring
//    [cell][b][8], per-WG private 128B generation flag lines, agent-relaxed
//    8B atomic ring access). R14's XCD grouping abandoned (undefined
//    mapping -> deadlock).
// ---------------------------------------------------------------------------

#define B_ 64
#define S_ 512
#define H_ 512
#define G3_ 1536

typedef __attribute__((ext_vector_type(8))) __bf16 bf16x8;
typedef __attribute__((ext_vector_type(8))) short short8;
typedef __attribute__((ext_vector_type(2))) unsigned long long ull2;
typedef __attribute__((ext_vector_type(4))) float f32x4;
typedef unsigned long long ull;

__device__ __forceinline__ unsigned short f2b(float f) {
  union { float f; unsigned int i; } v; v.f = f;
  unsigned int x = v.i;
  return (unsigned short)((x + 0x7fffu + ((x >> 16) & 1u)) >> 16);
}
__device__ __forceinline__ bf16x8 load8(const unsigned short* p) {
  short8 s = *(const short8*)p;
  return __builtin_bit_cast(bf16x8, s);
}
__device__ __forceinline__ bf16x8 load8f(const float* p) {
  f32x4 a = *(const f32x4*)p, b = *(const f32x4*)(p + 4);
  short8 s;
  s[0] = (short)f2b(a[0]); s[1] = (short)f2b(a[1]);
  s[2] = (short)f2b(a[2]); s[3] = (short)f2b(a[3]);
  s[4] = (short)f2b(b[0]); s[5] = (short)f2b(b[1]);
  s[6] = (short)f2b(b[2]); s[7] = (short)f2b(b[3]);
  return __builtin_bit_cast(bf16x8, s);
}
__device__ __forceinline__ f32x4 mfma16(bf16x8 a, bf16x8 b, f32x4 c) {
  return __builtin_amdgcn_mfma_f32_16x16x32_bf16(a, b, c, 0, 0, 0);
}
__device__ __forceinline__ float sigmoidf_(float x) {
  float e = __expf(-fabsf(x));
  float s = e / (1.0f + e);
  return x >= 0.0f ? 1.0f - s : s;
}
__device__ __forceinline__ float tanhf_(float x) {
  float e = __expf(-2.0f * fabsf(x));
  float r = (1.0f - e) / (1.0f + e);
  return x >= 0.0f ? r : -r;
}
// agent-scope coherent 16B (2x8B) ring read -> bf16x8
__device__ __forceinline__ bf16x8 load16a(ull* p) {
  ull2 v;
  v[0] = __hip_atomic_load(p, __ATOMIC_RELAXED, __HIP_MEMORY_SCOPE_AGENT);
  v[1] = __hip_atomic_load(p + 1, __ATOMIC_RELAXED, __HIP_MEMORY_SCOPE_AGENT);
  return __builtin_bit_cast(bf16x8, v);
}
__device__ __forceinline__ bf16x8 load16p(const ull* p) {
  ull2 v = *(const ull2*)p;
  return __builtin_bit_cast(bf16x8, v);
}

// ---------------------------------------------------------------------------
// xc[t][cell(64)][b(64)][8 bf16]  <-  x[b][t][cell*8+j]
// ---------------------------------------------------------------------------
__global__ void cvt_x(const float* __restrict__ x, ull* __restrict__ xc) {
  int i = blockIdx.x * 256 + threadIdx.x;      // 0 .. 2^21-1
  int b = i & 63, cell = (i >> 6) & 63, txx = i >> 12;
  const float* src = x + ((size_t)b * 512 + txx) * 512 + cell * 8;
  ull v0 = 0, v1 = 0;
#pragma unroll
  for (int j = 0; j < 4; ++j) v0 |= (ull)f2b(src[j]) << (16 * j);
#pragma unroll
  for (int j = 0; j < 4; ++j) v1 |= (ull)f2b(src[4 + j]) << (16 * j);
  size_t o = ((size_t)txx * 4096 + cell * 64 + b) * 2;
  xc[o] = v0;
  xc[o + 1] = v1;
}

// ---------------------------------------------------------------------------
// init ring slot 7 ("h before step 0") per gid.
// ring[gid(8)][slot(8)][cell(64)][b(32)][half(2)] ull
// ---------------------------------------------------------------------------
__global__ void init_ring(const float* __restrict__ enc, ull* __restrict__ ring) {
  int i = blockIdx.x * 256 + threadIdx.x;      // 0..32767
  if (i >= 32768) return;
  int gid = i >> 12;                           // 0..7
  int u = i & 4095;
  int d = (gid >> 1) & 1, beta = gid & 1;
  int half = u & 1, b = (u >> 1) & 31, cell = u >> 6;
  const float* e = enc + (size_t)(beta * 32 + b) * 1024 + d * 512 + cell * 8 + half * 4;
  ull v = 0;
#pragma unroll
  for (int j = 0; j < 4; ++j) v |= (ull)f2b(e[j]) << (16 * j);
  ring[(size_t)gid * 32768 + 7 * 4096 + u] = v;
}

// ---------------------------------------------------------------------------
// Persistent fused GRU. Grid 128 = l(2) x d(2) x cb(32), block 128 (2 waves).
// Each WG runs BOTH beta pipelines, phase-alternated per step.
// flags: [gid(8)][wg(32)] x 32 ints (private 128B line per WG), value = t+1.
// ---------------------------------------------------------------------------
__global__ __launch_bounds__(128) void gru_fused(
    const float* __restrict__ x,               // [B][S][H] f32 (fallback path)
    const ull* __restrict__ xc, int usexc,     // coalesced bf16 x
    const float* __restrict__ enc,
    const float* __restrict__ WihF, const float* __restrict__ WihB,
    const float* __restrict__ WhhF, const float* __restrict__ WhhB,
    const float* __restrict__ bihF, const float* __restrict__ bihB,
    const float* __restrict__ bhhF, const float* __restrict__ bhhB,
    ull* __restrict__ ring,
    unsigned int* __restrict__ flags,
    float* __restrict__ dout) {                // [B][S][2H] f32
  __shared__ __align__(16) unsigned short wih2[24576];  // [gate][kk][lane][8]
  __shared__ __align__(16) unsigned short whh2[24576];
  __shared__ float hpub[2][32 * 20];           // per-beta wave-local staging
  __shared__ __align__(16) float douts[2][8][32][20];   // l1 dout staging
  __shared__ int lcnt[2][8];

  const int tid = threadIdx.x;
  const int lane = tid & 63;
  const int wv = tid >> 6;                     // 0..1
  const int wg = (int)blockIdx.x;              // 0..127
  const int l = wg >> 6, d = (wg >> 5) & 1, cb = wg & 31;
  const int colbase = cb * 16;
  const int rowA = lane & 15, kb = lane >> 4;

  const float* Wih = (d ? WihB : WihF) + (size_t)l * G3_ * H_;
  const float* Whh = (d ? WhhB : WhhF) + (size_t)l * G3_ * H_;
  const float* bi = (d ? bihB : bihF) + l * G3_;
  const float* bh = (d ? bhhB : bhhF) + l * G3_;

  if (tid < 16) lcnt[tid >> 3][tid & 7] = 0;
  // one-time LDS fill, layout [gate(3)][kk(16)][lane(64)][8]
  for (int i = tid; i < 3072; i += 128) {
    int gate = i >> 10;
    int rest = i & 1023;
    int kk = rest >> 6;
    int l6 = rest & 63;
    int c = l6 & 15, k = l6 >> 4;
    size_t gro = (size_t)(gate * 512 + colbase + c) * 512 + kk * 32 + k * 8;
    *(short8*)&wih2[i * 8] = __builtin_bit_cast(short8, load8f(Wih + gro));
    *(short8*)&whh2[i * 8] = __builtin_bit_cast(short8, load8f(Whh + gro));
  }
  __syncthreads();                             // prologue only

  const int col16 = rowA;
  const int hc = colbase + col16;
  const float brz_r = bi[hc] + bh[hc];
  const float brz_z = bi[512 + hc] + bh[512 + hc];
  const float bi_n = bi[1024 + hc];
  const float bh_n = bh[1024 + hc];

  const int bq = wv * 16 + kb * 4;             // local batch rows (0..31)
  const int arow = wv * 16 + rowA;             // local A row (0..31)

  float hm[2][4];
#pragma unroll
  for (int be = 0; be < 2; ++be)
#pragma unroll
    for (int rg = 0; rg < 4; ++rg)
      hm[be][rg] = enc[(size_t)(be * 32 + bq + rg) * 1024 + d * 512 + hc];

  const int gidbase = (l * 2 + d) << 1;

  // publish mapping: one 8B word per thread (wave-local rows)
  const int pb = tid >> 2;                     // local batch 0..31
  const int pq = tid & 3;
  const int pcellL = pq >> 1, phalf = pq & 1;
  const int pidx = ((2 * cb + pcellL) * 32 + pb) * 2 + phalf;
  const int pc0 = pcellL * 8 + phalf * 4;

  for (int t = 0; t < 512; ++t) {
#pragma unroll
    for (int be = 0; be < 2; ++be) {
      const int gid = gidbase | be;
      unsigned int* flA = flags + (gid & 3) * 1024;        // l0 pipeline (d,be)
      unsigned int* flB = flags + ((gid & 3) | 4) * 1024;  // l1 pipeline (d,be)
      unsigned int* flo = flags + gid * 1024;
      ull* ringA = ring + (size_t)(gid & 3) * 32768;
      ull* ringl = ring + (size_t)gid * 32768;

      // x A-frags (layer 0): flag-independent — issue before the poll
      bf16x8 aIn[16];
      if (l == 0) {
        int txx = d ? (511 - t) : t;
        if (usexc) {
          const ull* xp = xc + (size_t)txx * 8192;
#pragma unroll
          for (int kk = 0; kk < 16; ++kk)
            aIn[kk] = load16p(xp + (size_t)((kk * 4 + kb) * 64 + be * 32 + arow) * 2);
        } else {
          const float* ap = x + ((size_t)(be * 32 + arow) * 512 + txx) * 512 + kb * 8;
#pragma unroll
          for (int kk = 0; kk < 16; ++kk) aIn[kk] = load8f(ap + kk * 32);
        }
      }

      // generation poll (R11 semantics):
      // l0: flA(own) >= t, flB >= t-7 (slot reuse guard)
      // l1: flA(producer) >= t+1, flB(own) >= t
      {
        const int needA = (l == 0) ? t : (t + 1);
        const int needB = (l == 0) ? (t - 7) : t;
        unsigned int* watch;
        int need;
        if (lane < 32) { watch = flA + lane * 32;        need = needA; }
        else           { watch = flB + (lane - 32) * 32; need = needB; }
        if (need > 0) {
          while (__hip_atomic_load(watch, __ATOMIC_RELAXED,
                                   __HIP_MEMORY_SCOPE_AGENT) < (unsigned)need) {}
        }
      }
      asm volatile("" ::: "memory");           // no hoisting of ring reads

      // ring reads (agent-relaxed 8B atomics — R11 proven path)
      bf16x8 aOwn[16];
      ull* rpo = ringl + (size_t)((t + 7) & 7) * 4096;   // own h_{t-1}
#pragma unroll
      for (int kk = 0; kk < 16; ++kk)
        aOwn[kk] = load16a(rpo + (size_t)((kk * 4 + kb) * 32 + arow) * 2);
      if (l == 1) {
        ull* rp = ringA + (size_t)(t & 7) * 4096;        // layer-0 h at step t
#pragma unroll
        for (int kk = 0; kk < 16; ++kk)
          aIn[kk] = load16a(rp + (size_t)((kk * 4 + kb) * 32 + arow) * 2);
      }

      f32x4 accr = {0,0,0,0}, accz = {0,0,0,0}, acni = {0,0,0,0}, acnh = {0,0,0,0};
#pragma unroll
      for (int kk = 0; kk < 16; ++kk) {
        const int o = kk * 512 + lane * 8;     // [kk][lane][8] within gate blk
        accr = mfma16(aIn[kk],  load8(&wih2[o]), accr);
        accr = mfma16(aOwn[kk], load8(&whh2[o]), accr);
        accz = mfma16(aIn[kk],  load8(&wih2[8192 + o]), accz);
        accz = mfma16(aOwn[kk], load8(&whh2[8192 + o]), accz);
        acni = mfma16(aIn[kk],  load8(&wih2[16384 + o]), acni);
        acnh = mfma16(aOwn[kk], load8(&whh2[16384 + o]), acnh);
      }

#pragma unroll
      for (int rg = 0; rg < 4; ++rg) {
        float r = sigmoidf_(accr[rg] + brz_r);
        float z = sigmoidf_(accz[rg] + brz_z);
        float n = tanhf_(acni[rg] + bi_n + r * (acnh[rg] + bh_n));
        float hnew = (1.0f - z) * n + z * hm[be][rg];
        hm[be][rg] = hnew;
        hpub[be][(bq + rg) * 20 + col16] = hnew;   // wave-local staging
        if (l == 1) douts[be][t & 7][bq + rg][col16] = hnew;
      }
      asm volatile("" ::: "memory");

      // publish own [32 b][16 col] slice to ring slot t&7 (1 word per thread)
      {
        f32x4 v4 = *(f32x4*)&hpub[be][pb * 20 + pc0];
        ull v = 0;
        v |= (ull)f2b(v4[0]);
        v |= (ull)f2b(v4[1]) << 16;
        v |= (ull)f2b(v4[2]) << 32;
        v |= (ull)f2b(v4[3]) << 48;
        __hip_atomic_store(ringl + (size_t)(t & 7) * 4096 + pidx, v,
                           __ATOMIC_RELAXED, __HIP_MEMORY_SCOPE_AGENT);
      }
      asm volatile("s_waitcnt vmcnt(0)" ::: "memory");   // ring store at IC

      // intra-WG arrival (2 waves); second wave bumps this WG's flag
      if (lane == 0) {
        int old = atomicAdd(&lcnt[be][t & 7], 1);
        if (old == 1) {
          lcnt[be][t & 7] = 0;
          __hip_atomic_store(flo + cb * 32, (unsigned)(t + 1),
                             __ATOMIC_RELAXED, __HIP_MEMORY_SCOPE_AGENT);
        }
      }

      // dout flush every 8 steps (coalesced 16B stores, off the drain path)
      if (l == 1 && (t & 7) == 7) {
        const int fb = tid >> 2;               // own wave's rows only
        const int fc = (tid & 3) * 4;
#pragma unroll
        for (int ts = 0; ts < 8; ++ts) {
          int tt = t - 7 + ts;
          int tox = d ? (511 - tt) : tt;
          f32x4 v = *(f32x4*)&douts[be][ts][fb][fc];
          *(f32x4*)&dout[((size_t)(be * 32 + fb) * 512 + tox) * 1024 +
                         d * 512 + colbase + fc] = v;
        }
      }
    }
  }
}

// ---------------------------------------------------------------------------
// Final hidden epilogue: h_f = out[:, S-1, :H], h_b = out[:, 0, H:2H]
// ---------------------------------------------------------------------------
__global__ void h_epi(float* __restrict__ dout) {
  int i = blockIdx.x * 256 + threadIdx.x;      // 0 .. 65535
  if (i >= B_ * 2 * H_) return;
  int b = i >> 10, j = i & 1023;
  int t = (j < H_) ? (S_ - 1) : 0;
  dout[(size_t)B_ * S_ * 2 * H_ + i] = dout[((size_t)b * S_ + t) * (2 * H_) + j];
}

// ---------------------------------------------------------------------------
extern "C" void kernel_launch(void* const* d_in, const int* in_sizes, int n_in,
                              void* d_out, int out_size, void* d_ws, size_t ws_size,
                              hipStream_t stream) {
  const float* x    = (const float*)d_in[0];
  const float* enc  = (const float*)d_in[1];
  const float* WihF = (const float*)d_in[2];
  const float* WhhF = (const float*)d_in[3];
  const float* bihF = (const float*)d_in[4];
  const float* bhhF = (const float*)d_in[5];
  const float* WihB = (const float*)d_in[6];
  const float* WhhB = (const float*)d_in[7];
  const float* bihB = (const float*)d_in[8];
  const float* bhhB = (const float*)d_in[9];
  float* out = (float*)d_out;

  // ws: [flags 32KB (+pad to 64KB)][ring 2MB][xc 32MB (optional)]
  char* ws = (char*)d_ws;
  unsigned int* flags = (unsigned int*)ws;     // 8*32*128B = 32,768 B
  ull* ring  = (ull*)(ws + 65536);             // 8 gids * 32768 ull = 2 MB
  ull* xc    = (ull*)(ws + 65536 + 2097152);   // 33,554,432 B
  const int usexc = (ws_size >= (size_t)65536 + 2097152 + 33554432) ? 1 : 0;

  (void)hipMemsetAsync(flags, 0, 32768, stream);
  if (usexc) cvt_x<<<8192, 256, 0, stream>>>(x, xc);
  init_ring<<<128, 256, 0, stream>>>(enc, ring);
  gru_fused<<<128, 128, 0, stream>>>(x, xc, usexc, enc,
                                     WihF, WihB, WhhF, WhhB,
                                     bihF, bihB, bhhF, bhhB,
                                     ring, flags, out);
  h_epi<<<256, 256, 0, stream>>>(out);
}

// Round 17
// 2306.767 us; speedup vs baseline: 1.7536x; 1.7536x over previous
//
#include <hip/hip_runtime.h>

// ---------------------------------------------------------------------------
// Bidirectional stacked GRU decoder. B=64, S=512, I=H=512, L=2. f32 I/O.
//
// FINAL (= round-11, the measured best: 2.33 ms, 42x over baseline).
//   grid 256 WGs x 128 thr = l(2) x d(2) x beta(2) x colslice(32).
//   Each WG: 16 cols x 32 batches; weights (Wih+Whh 16-col slices, bf16)
//   LDS-resident; h master in registers. 8 independent pipelines
//   (l0,d,beta)->(l1,d,beta); all-to-all only among the 32 colslices of a
//   pipeline; layer-1 lags layer-0 by 1 step (512-step critical path).
//   h exchanged via coalesced bf16 ring (depth 8) with agent-relaxed 8B
//   atomics; per-WG PRIVATE 128B generation flag lines (no shared cache
//   lines, no RMW on the critical path); dout stores after flag publish.
//
// Post-R11 structural attempts, all falsified (kept for the record):
//   R12 tagged ring, chunk-serial retry  -> 4.54 ms (dependent IC hops)
//   R13 16B bypass reads + dout staging  -> 2.44 ms (neutral: not BW-bound)
//   R14 XCD-local sync via XCC_ID        -> deadlock (WG->XCD undefined)
//   R15 dual-beta time-multiplexing      -> 4.05 ms (program-order serialized)
//   R16 tagged ring, parallel retry      -> GPU fault
// Residual cost = serial agent-scope publish->detect->read chain (~3 IC
// round-trips ~ 4.5us/step); not a memory/compute roofline.
// ---------------------------------------------------------------------------

#define B_ 64
#define S_ 512
#define H_ 512
#define G3_ 1536

typedef __attribute__((ext_vector_type(8))) __bf16 bf16x8;
typedef __attribute__((ext_vector_type(8))) short short8;
typedef __attribute__((ext_vector_type(2))) unsigned long long ull2;
typedef __attribute__((ext_vector_type(4))) float f32x4;
typedef unsigned long long ull;

__device__ __forceinline__ unsigned short f2b(float f) {
  union { float f; unsigned int i; } v; v.f = f;
  unsigned int x = v.i;
  return (unsigned short)((x + 0x7fffu + ((x >> 16) & 1u)) >> 16);
}
__device__ __forceinline__ bf16x8 load8(const unsigned short* p) {
  short8 s = *(const short8*)p;
  return __builtin_bit_cast(bf16x8, s);
}
__device__ __forceinline__ bf16x8 load8f(const float* p) {
  f32x4 a = *(const f32x4*)p, b = *(const f32x4*)(p + 4);
  short8 s;
  s[0] = (short)f2b(a[0]); s[1] = (short)f2b(a[1]);
  s[2] = (short)f2b(a[2]); s[3] = (short)f2b(a[3]);
  s[4] = (short)f2b(b[0]); s[5] = (short)f2b(b[1]);
  s[6] = (short)f2b(b[2]); s[7] = (short)f2b(b[3]);
  return __builtin_bit_cast(bf16x8, s);
}
__device__ __forceinline__ f32x4 mfma16(bf16x8 a, bf16x8 b, f32x4 c) {
  return __builtin_amdgcn_mfma_f32_16x16x32_bf16(a, b, c, 0, 0, 0);
}
__device__ __forceinline__ float sigmoidf_(float x) {
  float e = __expf(-fabsf(x));
  float s = e / (1.0f + e);
  return x >= 0.0f ? 1.0f - s : s;
}
__device__ __forceinline__ float tanhf_(float x) {
  float e = __expf(-2.0f * fabsf(x));
  float r = (1.0f - e) / (1.0f + e);
  return x >= 0.0f ? r : -r;
}
// agent-scope coherent 16B (2x8B) ring read -> bf16x8
__device__ __forceinline__ bf16x8 load16a(ull* p) {
  ull2 v;
  v[0] = __hip_atomic_load(p, __ATOMIC_RELAXED, __HIP_MEMORY_SCOPE_AGENT);
  v[1] = __hip_atomic_load(p + 1, __ATOMIC_RELAXED, __HIP_MEMORY_SCOPE_AGENT);
  return __builtin_bit_cast(bf16x8, v);
}
__device__ __forceinline__ bf16x8 load16p(const ull* p) {
  ull2 v = *(const ull2*)p;
  return __builtin_bit_cast(bf16x8, v);
}
__device__ __forceinline__ ull pack4(const float* f) {
  ull v = 0;
#pragma unroll
  for (int j = 0; j < 4; ++j) v |= (ull)f2b(f[j]) << (16 * j);
  return v;
}

// ---------------------------------------------------------------------------
// xc[t][cell(64)][b(64)][8 bf16]  <-  x[b][t][cell*8+j]
// ---------------------------------------------------------------------------
__global__ void cvt_x(const float* __restrict__ x, ull* __restrict__ xc) {
  int i = blockIdx.x * 256 + threadIdx.x;      // 0 .. 2^21-1
  int b = i & 63, cell = (i >> 6) & 63, txx = i >> 12;
  const float* src = x + ((size_t)b * 512 + txx) * 512 + cell * 8;
  float s0[4] = {src[0], src[1], src[2], src[3]};
  float s1[4] = {src[4], src[5], src[6], src[7]};
  size_t o = ((size_t)txx * 4096 + cell * 64 + b) * 2;
  xc[o]     = pack4(s0);
  xc[o + 1] = pack4(s1);
}

// ---------------------------------------------------------------------------
// init ring slot 7 ("h before step 0") per gid.
// ring[gid(8)][slot(8)][cell(64)][b(32)][half(2)] ull;  gid = [l d beta]
// ---------------------------------------------------------------------------
__global__ void init_ring(const float* __restrict__ enc, ull* __restrict__ ring) {
  int i = blockIdx.x * 256 + threadIdx.x;      // 0..32767
  if (i >= 32768) return;
  int gid = i >> 12;                           // 0..7
  int u = i & 4095;
  int d = (gid >> 1) & 1, beta = gid & 1;
  int half = u & 1, b = (u >> 1) & 31, cell = u >> 6;
  const float* e = enc + (size_t)(beta * 32 + b) * 1024 + d * 512 + cell * 8 + half * 4;
  float s[4] = {e[0], e[1], e[2], e[3]};
  ring[(size_t)gid * 32768 + 7 * 4096 + u] = pack4(s);
}

// ---------------------------------------------------------------------------
// Persistent fused GRU. Grid 256 = l(2) x d(2) x beta(2) x cb(32), block 128.
// flags: [gid(8)][wg(32)] x 32 ints (private 128B line per WG), value = t+1.
// ---------------------------------------------------------------------------
__global__ __launch_bounds__(128) void gru_fused(
    const float* __restrict__ x,               // [B][S][H] f32 (fallback path)
    const ull* __restrict__ xc, int usexc,     // coalesced bf16 x
    const float* __restrict__ enc,
    const float* __restrict__ WihF, const float* __restrict__ WihB,
    const float* __restrict__ WhhF, const float* __restrict__ WhhB,
    const float* __restrict__ bihF, const float* __restrict__ bihB,
    const float* __restrict__ bhhF, const float* __restrict__ bhhB,
    ull* __restrict__ ring,
    unsigned int* __restrict__ flags,
    float* __restrict__ dout) {                // [B][S][2H] f32
  __shared__ __align__(16) unsigned short wih2[24576];  // [gate][kk][lane][8]
  __shared__ __align__(16) unsigned short whh2[24576];
  __shared__ float hpub[32 * 20];              // [b_local][20] padded
  __shared__ int lcnt[8];

  const int tid = threadIdx.x;
  const int lane = tid & 63;
  const int wv = tid >> 6;                     // 0..1
  const int wg = (int)blockIdx.x;
  const int l = wg >> 7, d = (wg >> 6) & 1, beta = (wg >> 5) & 1, cb = wg & 31;
  const int gid = ((l * 2 + d) << 1) | beta;   // [l d beta]
  const int gidA = gid & 3;                    // l0 pipeline partner
  const int gidB = gidA | 4;                   // l1 pipeline partner
  const int colbase = cb * 16;
  const int rowA = lane & 15, kb = lane >> 4;

  const float* Wih = (d ? WihB : WihF) + (size_t)l * G3_ * H_;
  const float* Whh = (d ? WhhB : WhhF) + (size_t)l * G3_ * H_;
  const float* bi = (d ? bihB : bihF) + l * G3_;
  const float* bh = (d ? bhhB : bhhF) + l * G3_;

  if (tid < 8) lcnt[tid] = 0;
  // one-time LDS fill, layout [gate(3)][kk(16)][lane(64)][8]
  for (int i = tid; i < 3072; i += 128) {
    int gate = i >> 10;
    int rest = i & 1023;
    int kk = rest >> 6;
    int l6 = rest & 63;
    int c = l6 & 15, k = l6 >> 4;
    size_t gro = (size_t)(gate * 512 + colbase + c) * 512 + kk * 32 + k * 8;
    *(short8*)&wih2[i * 8] = __builtin_bit_cast(short8, load8f(Wih + gro));
    *(short8*)&whh2[i * 8] = __builtin_bit_cast(short8, load8f(Whh + gro));
  }
  __syncthreads();                             // prologue only

  const int col16 = rowA;
  const int hc = colbase + col16;
  const float brz_r = bi[hc] + bh[hc];
  const float brz_z = bi[512 + hc] + bh[512 + hc];
  const float bi_n = bi[1024 + hc];
  const float bh_n = bh[1024 + hc];

  const int bq = wv * 16 + kb * 4;             // local batch rows (0..31)
  const int arow = wv * 16 + rowA;             // local A row (0..31)

  float hm[4];
#pragma unroll
  for (int rg = 0; rg < 4; ++rg)
    hm[rg] = enc[(size_t)(beta * 32 + bq + rg) * 1024 + d * 512 + hc];

  unsigned int* flA = flags + gidA * 1024;     // 32 lines x 32 ints
  unsigned int* flB = flags + gidB * 1024;
  unsigned int* flo = flags + gid * 1024;
  ull* ringA = ring + (size_t)gidA * 32768;
  ull* ringl = ring + (size_t)gid * 32768;

  // publish mapping: one 8B word per thread
  const int pb = tid >> 2;                     // local batch 0..31
  const int pq = tid & 3;
  const int pcellL = pq >> 1, phalf = pq & 1;
  const int pc0 = pcellL * 8 + phalf * 4;
  const int pidx = ((2 * cb + pcellL) * 32 + pb) * 2 + phalf;

  for (int t = 0; t < 512; ++t) {
    // x A-frags (layer 0): flag-independent — issue before the poll
    bf16x8 aIn[16];
    if (l == 0) {
      int txx = d ? (511 - t) : t;
      if (usexc) {
        const ull* xp = xc + (size_t)txx * 8192;
#pragma unroll
        for (int kk = 0; kk < 16; ++kk)
          aIn[kk] = load16p(xp + (size_t)((kk * 4 + kb) * 64 + beta * 32 + arow) * 2);
      } else {
        const float* ap = x + ((size_t)(beta * 32 + arow) * 512 + txx) * 512 + kb * 8;
#pragma unroll
        for (int kk = 0; kk < 16; ++kk) aIn[kk] = load8f(ap + kk * 32);
      }
    }

    // generation poll (both waves poll; lanes watch private lines)
    // l0: flA(own) >= t, flB >= t-7 (slot reuse guard)
    // l1: flA(producer) >= t+1, flB(own) >= t
    {
      const int needA = (l == 0) ? t : (t + 1);
      const int needB = (l == 0) ? (t - 7) : t;
      unsigned int* watch;
      int need;
      if (lane < 32) { watch = flA + lane * 32;        need = needA; }
      else           { watch = flB + (lane - 32) * 32; need = needB; }
      if (need > 0) {
        while (__hip_atomic_load(watch, __ATOMIC_RELAXED,
                                 __HIP_MEMORY_SCOPE_AGENT) < (unsigned)need) {}
      }
    }
    asm volatile("" ::: "memory");             // no hoisting of ring reads

    if (l == 1) {                              // layer-0 output at step t
      ull* rp = ringA + (size_t)(t & 7) * 4096;
#pragma unroll
      for (int kk = 0; kk < 16; ++kk)
        aIn[kk] = load16a(rp + (size_t)((kk * 4 + kb) * 32 + arow) * 2);
    }
    ull* rpo = ringl + (size_t)((t + 7) & 7) * 4096;   // own h_{t-1}
    bf16x8 aOwn[16];
#pragma unroll
    for (int kk = 0; kk < 16; ++kk)
      aOwn[kk] = load16a(rpo + (size_t)((kk * 4 + kb) * 32 + arow) * 2);

    f32x4 accr = {0,0,0,0}, accz = {0,0,0,0}, acni = {0,0,0,0}, acnh = {0,0,0,0};
#pragma unroll
    for (int kk = 0; kk < 16; ++kk) {
      const int o = kk * 512 + lane * 8;       // [kk][lane][8] within gate blk
      accr = mfma16(aIn[kk],  load8(&wih2[o]), accr);
      accr = mfma16(aOwn[kk], load8(&whh2[o]), accr);
      accz = mfma16(aIn[kk],  load8(&wih2[8192 + o]), accz);
      accz = mfma16(aOwn[kk], load8(&whh2[8192 + o]), accz);
      acni = mfma16(aIn[kk],  load8(&wih2[16384 + o]), acni);
      acnh = mfma16(aOwn[kk], load8(&whh2[16384 + o]), acnh);
    }

#pragma unroll
    for (int rg = 0; rg < 4; ++rg) {
      float r = sigmoidf_(accr[rg] + brz_r);
      float z = sigmoidf_(accz[rg] + brz_z);
      float n = tanhf_(acni[rg] + bi_n + r * (acnh[rg] + bh_n));
      float hnew = (1.0f - z) * n + z * hm[rg];
      hm[rg] = hnew;
      hpub[(bq + rg) * 20 + col16] = hnew;     // wave-local staging
    }
    asm volatile("" ::: "memory");

    // publish own [32 b][16 col] slice to ring slot t&7 (1 word per thread)
    {
      f32x4 v4 = *(f32x4*)&hpub[pb * 20 + pc0];
      float s[4] = {v4[0], v4[1], v4[2], v4[3]};
      __hip_atomic_store(ringl + (size_t)(t & 7) * 4096 + pidx, pack4(s),
                         __ATOMIC_RELAXED, __HIP_MEMORY_SCOPE_AGENT);
    }
    asm volatile("s_waitcnt vmcnt(0)" ::: "memory");   // ring store at IC

    // intra-WG arrival (2 waves); second wave bumps this WG's generation flag
    if (lane == 0) {
      int old = atomicAdd(&lcnt[t & 7], 1);
      if (old == 1) {
        lcnt[t & 7] = 0;
        __hip_atomic_store(flo + cb * 32, (unsigned)(t + 1),
                           __ATOMIC_RELAXED, __HIP_MEMORY_SCOPE_AGENT);
      }
    }

    // dout stores AFTER the flag publish — off the critical chain
    if (l == 1) {
      const int tox = d ? (511 - t) : t;
#pragma unroll
      for (int rg = 0; rg < 4; ++rg)
        dout[((size_t)(beta * 32 + bq + rg) * 512 + tox) * 1024 + d * 512 + hc] = hm[rg];
    }
  }
}

// ---------------------------------------------------------------------------
// Final hidden epilogue: h_f = out[:, S-1, :H], h_b = out[:, 0, H:2H]
// ---------------------------------------------------------------------------
__global__ void h_epi(float* __restrict__ dout) {
  int i = blockIdx.x * 256 + threadIdx.x;      // 0 .. 65535
  if (i >= B_ * 2 * H_) return;
  int b = i >> 10, j = i & 1023;
  int t = (j < H_) ? (S_ - 1) : 0;
  dout[(size_t)B_ * S_ * 2 * H_ + i] = dout[((size_t)b * S_ + t) * (2 * H_) + j];
}

// ---------------------------------------------------------------------------
extern "C" void kernel_launch(void* const* d_in, const int* in_sizes, int n_in,
                              void* d_out, int out_size, void* d_ws, size_t ws_size,
                              hipStream_t stream) {
  const float* x    = (const float*)d_in[0];
  const float* enc  = (const float*)d_in[1];
  const float* WihF = (const float*)d_in[2];
  const float* WhhF = (const float*)d_in[3];
  const float* bihF = (const float*)d_in[4];
  const float* bhhF = (const float*)d_in[5];
  const float* WihB = (const float*)d_in[6];
  const float* WhhB = (const float*)d_in[7];
  const float* bihB = (const float*)d_in[8];
  const float* bhhB = (const float*)d_in[9];
  float* out = (float*)d_out;

  // ws: [flags 32KB (+pad to 64KB)][ring 2MB][xc 32MB (optional)]
  char* ws = (char*)d_ws;
  unsigned int* flags = (unsigned int*)ws;     // 8*32*128B = 32,768 B
  ull* ring  = (ull*)(ws + 65536);             // 8 gids * 32768 * 8B = 2,097,152 B
  ull* xc    = (ull*)(ws + 65536 + 2097152);   // 33,554,432 B
  const int usexc = (ws_size >= (size_t)65536 + 2097152 + 33554432) ? 1 : 0;

  (void)hipMemsetAsync(flags, 0, 32768, stream);
  if (usexc) cvt_x<<<8192, 256, 0, stream>>>(x, xc);
  init_ring<<<128, 256, 0, stream>>>(enc, ring);
  gru_fused<<<256, 128, 0, stream>>>(x, xc, usexc, enc,
                                     WihF, WihB, WhhF, WhhB,
                                     bihF, bihB, bhhF, bhhB,
                                     ring, flags, out);
  h_epi<<<256, 256, 0, stream>>>(out);
}